// Round 1
// baseline (432.346 us; speedup 1.0000x reference)
//
#include <hip/hip_runtime.h>

#define NE 11
#define NP 64
#define NC 128
#define NHW 4096
#define NHID 512
#define NB 8

typedef __attribute__((ext_vector_type(8))) __bf16 bf16x8;
typedef __attribute__((ext_vector_type(4))) float f32x4;

__device__ __forceinline__ unsigned short f2bf(float f) {
    unsigned u = __float_as_uint(f);
    unsigned r = (u + 0x7fffu + ((u >> 16) & 1u)) >> 16;
    return (unsigned short)r;
}

__device__ __forceinline__ float gelu_f(float v) {
    return 0.5f * v * (1.0f + erff(v * 0.70710678118654752440f));
}

// LDS B-fragment read: row-major [row][128] bf16 tile, XOR-swizzled (G4 recipe)
__device__ __forceinline__ bf16x8 ldsB(const unsigned short* basep, int row, int col) {
    int byteoff = ((row << 8) + (col << 1)) ^ ((row & 7) << 4);
    return *(const bf16x8*)((const char*)basep + byteoff);
}

// ---------------- kernel 1: weight fp32 -> bf16 ----------------
__global__ void k_cvt(const float* __restrict__ ew1, const float* __restrict__ ew2,
                      unsigned short* __restrict__ o1, unsigned short* __restrict__ o2) {
    const int n = NE * NHID * NC; // 720896 (same for both)
    for (int i = blockIdx.x * 256 + threadIdx.x; i < n; i += gridDim.x * 256) {
        o1[i] = f2bf(ew1[i]);
        o2[i] = f2bf(ew2[i]);
    }
}

// ---------------- kernel 2: global context pool ----------------
__global__ void k_gc(const float* __restrict__ x, float* __restrict__ gc) {
    int row = blockIdx.x; // b*128+c
    const float* p = x + (size_t)row * NHW;
    float s = 0.f;
    for (int i = threadIdx.x; i < NHW; i += 256) s += p[i];
    __shared__ float red[256];
    red[threadIdx.x] = s;
    __syncthreads();
    for (int off = 128; off > 0; off >>= 1) {
        if (threadIdx.x < off) red[threadIdx.x] += red[threadIdx.x + off];
        __syncthreads();
    }
    if (threadIdx.x == 0) gc[row] = red[0] * (1.0f / 4096.0f);
}

// ---------------- kernel 3: tiny attention path + ortho + stat zero ----------------
__global__ void k_attn(const float* __restrict__ gc, const float* __restrict__ proto,
                       const float* __restrict__ ctx_w, const float* __restrict__ ctx_b,
                       const float* __restrict__ wq, const float* __restrict__ bq,
                       const float* __restrict__ wk, const float* __restrict__ bk,
                       const float* __restrict__ wv, const float* __restrict__ bv,
                       const float* __restrict__ wo, const float* __restrict__ bo,
                       const float* __restrict__ lng, const float* __restrict__ lnb,
                       float* __restrict__ up, float* __restrict__ ortho, float* __restrict__ stats) {
    int t = threadIdx.x;
    __shared__ float seq[12][64], qs[12][64], ks_[12][64], vs[12][64], ao[12][64], rr[12][64];
    __shared__ float nr[NE], sq[NE * NE];

    if (blockIdx.x == 8) { // ortho + zero stats
        if (t < 22) stats[t] = 0.0f;
        if (t < NE) {
            float s = 0.f;
            for (int p = 0; p < NP; p++) { float v = proto[t * NP + p]; s += v * v; }
            nr[t] = rsqrtf(s);
        }
        __syncthreads();
        if (t < NE * NE) {
            int i = t / NE, j = t % NE;
            float d = 0.f;
            for (int p = 0; p < NP; p++) d += proto[i * NP + p] * proto[j * NP + p];
            float c = d * nr[i] * nr[j] - (i == j ? 1.0f : 0.0f);
            sq[t] = c * c;
        }
        __syncthreads();
        if (t == 0) {
            float s = 0.f;
            for (int i = 0; i < NE * NE; i++) s += sq[i];
            *ortho = sqrtf(s);
        }
        return;
    }

    int b = blockIdx.x;
    // seq[0] = gc @ ctx_w^T + ctx_b ; seq[1..11] = proto
    if (t < NP) {
        float a = ctx_b[t];
        for (int c = 0; c < NC; c++) a = fmaf(gc[b * NC + c], ctx_w[t * NC + c], a);
        seq[0][t] = a;
    }
    for (int i = t; i < NE * NP; i += 256) { int e = i >> 6, p = i & 63; seq[e + 1][p] = proto[e * NP + p]; }
    __syncthreads();
    // qkv
    for (int i = t; i < 12 * NP; i += 256) {
        int s = i >> 6, p = i & 63;
        float aq = bq[p], ak = bk[p], av = bv[p];
        for (int pp = 0; pp < NP; pp++) {
            float sv = seq[s][pp];
            aq = fmaf(sv, wq[p * NP + pp], aq);
            ak = fmaf(sv, wk[p * NP + pp], ak);
            av = fmaf(sv, wv[p * NP + pp], av);
        }
        qs[s][p] = aq; ks_[s][p] = ak; vs[s][p] = av;
    }
    __syncthreads();
    // attention per (head, query)
    if (t < 48) {
        int h = t / 12, qq = t % 12;
        float sc[12], m = -1e30f;
        for (int kk = 0; kk < 12; kk++) {
            float s = 0.f;
            for (int d = 0; d < 16; d++) s = fmaf(qs[qq][h * 16 + d], ks_[kk][h * 16 + d], s);
            s *= 0.25f; // 1/sqrt(16)
            sc[kk] = s;
            if (s > m) m = s;
        }
        float den = 0.f;
        for (int kk = 0; kk < 12; kk++) { sc[kk] = expf(sc[kk] - m); den += sc[kk]; }
        float inv = 1.0f / den;
        for (int d = 0; d < 16; d++) {
            float a = 0.f;
            for (int kk = 0; kk < 12; kk++) a = fmaf(sc[kk], vs[kk][h * 16 + d], a);
            ao[qq][h * 16 + d] = a * inv;
        }
    }
    __syncthreads();
    // out proj + residual
    for (int i = t; i < 12 * NP; i += 256) {
        int s = i >> 6, p = i & 63;
        float a = bo[p];
        for (int pp = 0; pp < NP; pp++) a = fmaf(ao[s][pp], wo[p * NP + pp], a);
        rr[s][p] = a + seq[s][p];
    }
    __syncthreads();
    // layernorm, emit up = seq2[:,1:,:]
    if (t < 12) {
        int s = t;
        float m = 0.f;
        for (int p = 0; p < NP; p++) m += rr[s][p];
        m *= (1.0f / 64.0f);
        float v = 0.f;
        for (int p = 0; p < NP; p++) { float d = rr[s][p] - m; v += d * d; }
        v *= (1.0f / 64.0f);
        float is = rsqrtf(v + 1e-5f);
        if (s >= 1)
            for (int p = 0; p < NP; p++)
                up[(b * NE + s - 1) * NP + p] = (rr[s][p] - m) * is * lng[p] + lnb[p];
    }
}

// ---------------- kernel 4: fused gating + MoE experts ----------------
__global__ __launch_bounds__(256, 2) void k_main(
    const float* __restrict__ x, const float* __restrict__ inp_w, const float* __restrict__ inp_b,
    const unsigned short* __restrict__ ew1b, const float* __restrict__ eb1,
    const unsigned short* __restrict__ ew2b, const float* __restrict__ eb2,
    const float* __restrict__ upw, float* __restrict__ stats, float* __restrict__ out) {
    int tid = threadIdx.x;
    int bimg = blockIdx.x >> 6;
    int pix0 = (blockIdx.x & 63) << 6; // 64 pixels per block
    int wid = tid >> 6;
    int l15 = tid & 15;
    int l4 = (tid >> 4) & 3;

    __shared__ __align__(16) unsigned short xs[64 * 128]; // [pix][c] bf16, swizzled
    __shared__ __align__(16) unsigned short hs[64 * 128]; // [pix][o_local] bf16, swizzled
    __shared__ float stage[32 * 64];
    __shared__ float lpart[4][NE][64];
    __shared__ float upl[NE * NP];
    __shared__ float wm[NE * 64];
    __shared__ float pb[NE * 64];
    __shared__ unsigned smask[64];
    __shared__ float eb1c[128], eb2l[128];
    __shared__ int eflag[NE];

    // ---- phase 0: stage x (fp32 chunks + bf16 tile) and fp32 gating ----
    for (int i = tid; i < NE * NP; i += 256) upl[i] = upw[bimg * (NE * NP) + i];
    int pixl = tid & 63;
    int pg = wid; // p-range pg*16..pg*16+15
    float xr[16];
#pragma unroll
    for (int p = 0; p < 16; p++) xr[p] = inp_b[pg * 16 + p];

    for (int cb = 0; cb < NC; cb += 32) {
        for (int i = tid; i < 32 * 64; i += 256) {
            int cc = i >> 6, px = i & 63;
            float v = x[(size_t)(bimg * NC + cb + cc) * NHW + pix0 + px];
            stage[cc * 64 + px] = v;
            int byteoff = ((px << 8) + ((cb + cc) << 1)) ^ ((px & 7) << 4);
            *(unsigned short*)((char*)xs + byteoff) = f2bf(v);
        }
        __syncthreads();
#pragma unroll 4
        for (int cc = 0; cc < 32; cc++) {
            float xv = stage[cc * 64 + pixl];
#pragma unroll
            for (int p = 0; p < 16; p++)
                xr[p] = fmaf(inp_w[(pg * 16 + p) * NC + cb + cc], xv, xr[p]);
        }
        __syncthreads();
    }
    for (int e = 0; e < NE; e++) {
        float a = 0.f;
#pragma unroll
        for (int p = 0; p < 16; p++) a = fmaf(upl[e * NP + pg * 16 + p], xr[p], a);
        lpart[pg][e][pixl] = a;
    }
    __syncthreads();

    // per-pixel softmax + top-6 (fp32 exact)
    if (tid < 64) {
        float pr[NE];
        float mx = -1e30f;
        for (int e = 0; e < NE; e++) {
            float l = (lpart[0][e][tid] + lpart[1][e][tid] + lpart[2][e][tid] + lpart[3][e][tid]) * 0.125f;
            pr[e] = l;
            if (l > mx) mx = l;
        }
        float den = 0.f;
        for (int e = 0; e < NE; e++) { pr[e] = expf(pr[e] - mx); den += pr[e]; }
        float inv = 1.0f / den;
        for (int e = 0; e < NE; e++) { pr[e] *= inv; pb[e * 64 + tid] = pr[e]; }
        unsigned used = 0;
        float tvsum = 0.f;
        float wloc[NE];
        for (int e = 0; e < NE; e++) wloc[e] = 0.f;
        for (int k = 0; k < 6; k++) { // strict > keeps lowest index on ties (matches lax.top_k)
            int best = 0;
            float bv = -1.0f;
            for (int e = 0; e < NE; e++)
                if (!((used >> e) & 1) && pr[e] > bv) { bv = pr[e]; best = e; }
            used |= 1u << best;
            wloc[best] = bv;
            tvsum += bv;
        }
        float itv = 1.0f / tvsum;
        for (int e = 0; e < NE; e++) wm[e * 64 + tid] = wloc[e] * itv;
        smask[tid] = used;
    }
    __syncthreads();
    if (tid < NE) {
        float sp = 0.f;
        int cnt = 0;
        for (int px = 0; px < 64; px++) {
            sp += pb[tid * 64 + px];
            cnt += (smask[px] >> tid) & 1;
        }
        atomicAdd(&stats[tid], sp);
        atomicAdd(&stats[NE + tid], (float)cnt);
        eflag[tid] = cnt;
    }
    __syncthreads();

    // ---- phase 1: experts via bf16 MFMA, o-chunked at 128 ----
    float outacc[2][4][4];
    for (int ct = 0; ct < 2; ct++)
        for (int nt = 0; nt < 4; nt++)
            for (int r = 0; r < 4; r++) outacc[ct][nt][r] = 0.f;

    for (int e = 0; e < NE; e++) {
        if (eflag[e] == 0) continue;
        __syncthreads(); // protect eb2l vs previous expert's accumulate reads
        if (tid < 128) eb2l[tid] = eb2[e * NC + tid];
        f32x4 acc2[2][4];
        for (int ct = 0; ct < 2; ct++)
            for (int nt = 0; nt < 4; nt++)
                for (int r = 0; r < 4; r++) acc2[ct][nt][r] = 0.f;

        for (int j = 0; j < 4; j++) { // o-chunk of 128
            if (tid < 128) eb1c[tid] = eb1[e * NHID + j * 128 + tid];
            // layer 1: A = ew1[o][c] streamed from L2, B = xs
            bf16x8 a1[2][4];
#pragma unroll
            for (int ot = 0; ot < 2; ot++)
#pragma unroll
                for (int ksp = 0; ksp < 4; ksp++) {
                    const unsigned short* src =
                        ew1b + (size_t)(e * NHID + j * 128 + (wid * 2 + ot) * 16 + l15) * NC + ksp * 32 + l4 * 8;
                    a1[ot][ksp] = *(const bf16x8*)src;
                }
            f32x4 acc1[2][4];
            for (int ot = 0; ot < 2; ot++)
                for (int nt = 0; nt < 4; nt++)
                    for (int r = 0; r < 4; r++) acc1[ot][nt][r] = 0.f;
#pragma unroll
            for (int nt = 0; nt < 4; nt++) {
#pragma unroll
                for (int ksp = 0; ksp < 4; ksp++) {
                    bf16x8 bf = ldsB(xs, nt * 16 + l15, ksp * 32 + l4 * 8);
                    acc1[0][nt] = __builtin_amdgcn_mfma_f32_16x16x32_bf16(a1[0][ksp], bf, acc1[0][nt], 0, 0, 0);
                    acc1[1][nt] = __builtin_amdgcn_mfma_f32_16x16x32_bf16(a1[1][ksp], bf, acc1[1][nt], 0, 0, 0);
                }
            }
            __syncthreads(); // eb1c staged; prior layer-2 hs reads complete
            // bias + exact gelu + pack to hs (bf16, swizzled)
#pragma unroll
            for (int ot = 0; ot < 2; ot++)
                for (int nt = 0; nt < 4; nt++) {
                    int oloc = (wid * 2 + ot) * 16 + l4 * 4;
                    int px = nt * 16 + l15;
                    unsigned short h4[4];
#pragma unroll
                    for (int r = 0; r < 4; r++) {
                        float v = acc1[ot][nt][r] + eb1c[oloc + r];
                        h4[r] = f2bf(gelu_f(v));
                    }
                    unsigned lo = (unsigned)h4[0] | ((unsigned)h4[1] << 16);
                    unsigned hi = (unsigned)h4[2] | ((unsigned)h4[3] << 16);
                    int byteoff = ((px << 8) + (oloc << 1)) ^ ((px & 7) << 4);
                    *(uint2*)((char*)hs + byteoff) = make_uint2(lo, hi);
                }
            __syncthreads(); // hs ready
            // layer 2: A = ew2[c][o] streamed, B = hs; Y accumulates across chunks
            bf16x8 a2[2][4];
#pragma unroll
            for (int ct = 0; ct < 2; ct++)
#pragma unroll
                for (int ksp = 0; ksp < 4; ksp++) {
                    const unsigned short* src =
                        ew2b + (size_t)(e * NC + (wid * 2 + ct) * 16 + l15) * NHID + j * 128 + ksp * 32 + l4 * 8;
                    a2[ct][ksp] = *(const bf16x8*)src;
                }
#pragma unroll
            for (int nt = 0; nt < 4; nt++) {
#pragma unroll
                for (int ksp = 0; ksp < 4; ksp++) {
                    bf16x8 bf = ldsB(hs, nt * 16 + l15, ksp * 32 + l4 * 8);
                    acc2[0][nt] = __builtin_amdgcn_mfma_f32_16x16x32_bf16(a2[0][ksp], bf, acc2[0][nt], 0, 0, 0);
                    acc2[1][nt] = __builtin_amdgcn_mfma_f32_16x16x32_bf16(a2[1][ksp], bf, acc2[1][nt], 0, 0, 0);
                }
            }
        }
        // masked accumulate
#pragma unroll
        for (int ct = 0; ct < 2; ct++)
            for (int nt = 0; nt < 4; nt++) {
                int px = nt * 16 + l15;
                float w = wm[e * 64 + px];
                int cg = (wid * 2 + ct) * 16 + l4 * 4;
#pragma unroll
                for (int r = 0; r < 4; r++)
                    outacc[ct][nt][r] = fmaf(w, acc2[ct][nt][r] + eb2l[cg + r], outacc[ct][nt][r]);
            }
    }

    // ---- epilogue: out = x + final ----
#pragma unroll
    for (int ct = 0; ct < 2; ct++)
        for (int nt = 0; nt < 4; nt++) {
            int px = pix0 + nt * 16 + l15;
#pragma unroll
            for (int r = 0; r < 4; r++) {
                int c = (wid * 2 + ct) * 16 + l4 * 4 + r;
                size_t g = (size_t)(bimg * NC + c) * NHW + px;
                out[g] = x[g] + outacc[ct][nt][r];
            }
        }
}

// ---------------- kernel 5: aux scalar ----------------
__global__ void k_final(const float* __restrict__ stats, const float* __restrict__ ortho,
                        float* __restrict__ out) {
    if (threadIdx.x == 0 && blockIdx.x == 0) {
        float aux = 0.f;
        for (int e = 0; e < NE; e++)
            aux += (stats[e] * (1.0f / 32768.0f)) * (stats[NE + e] * (1.0f / 32768.0f));
        aux *= (float)NE;
        out[4194304] = aux + 0.5f * (*ortho);
    }
}

extern "C" void kernel_launch(void* const* d_in, const int* in_sizes, int n_in,
                              void* d_out, int out_size, void* d_ws, size_t ws_size,
                              hipStream_t stream) {
    const float* x = (const float*)d_in[0];
    const float* proto = (const float*)d_in[1];
    const float* ctx_w = (const float*)d_in[2];
    const float* ctx_b = (const float*)d_in[3];
    const float* inp_w = (const float*)d_in[4];
    const float* inp_b = (const float*)d_in[5];
    const float* wq = (const float*)d_in[6];
    const float* bq = (const float*)d_in[7];
    const float* wk = (const float*)d_in[8];
    const float* bk = (const float*)d_in[9];
    const float* wv = (const float*)d_in[10];
    const float* bv = (const float*)d_in[11];
    const float* wo = (const float*)d_in[12];
    const float* bo = (const float*)d_in[13];
    const float* lng = (const float*)d_in[14];
    const float* lnb = (const float*)d_in[15];
    const float* ew1 = (const float*)d_in[16];
    const float* eb1 = (const float*)d_in[17];
    const float* ew2 = (const float*)d_in[18];
    const float* eb2 = (const float*)d_in[19];
    float* out = (float*)d_out;
    float* ws = (float*)d_ws;

    float* gc = ws;           // 1024 floats
    float* up = ws + 1024;    // 8*11*64 = 5632
    float* ortho = ws + 6656; // 1
    float* stats = ws + 6657; // 22 (sum_probs[11], load_cnt[11])
    unsigned short* ew1b = (unsigned short*)(ws + 8192); // 720896 ushorts
    unsigned short* ew2b = ew1b + NE * NHID * NC;        // 720896 ushorts

    k_cvt<<<512, 256, 0, stream>>>(ew1, ew2, ew1b, ew2b);
    k_gc<<<1024, 256, 0, stream>>>(x, gc);
    k_attn<<<9, 256, 0, stream>>>(gc, proto, ctx_w, ctx_b, wq, bq, wk, bk, wv, bv, wo, bo, lng, lnb,
                                  up, ortho, stats);
    k_main<<<512, 256, 0, stream>>>(x, inp_w, inp_b, ew1b, eb1, ew2b, eb2, up, stats, out);
    k_final<<<1, 64, 0, stream>>>(stats, ortho, out);
}